// Round 13
// baseline (171.873 us; speedup 1.0000x reference)
//
#include <hip/hip_runtime.h>
#include <hip/hip_bf16.h>

using bf16 = __hip_bfloat16;
using bf16x8 = __attribute__((ext_vector_type(8))) short;
using f32x4  = __attribute__((ext_vector_type(4))) float;

__device__ inline unsigned short f2bu(float f){ bf16 h = __float2bfloat16(f); return *(unsigned short*)&h; }
__device__ inline void async_cp16(const void* g, void* l){
  __builtin_amdgcn_global_load_lds((const __attribute__((address_space(1))) void*)g,
                                   (__attribute__((address_space(3))) void*)l, 16, 0, 0);
}
union BF8 { unsigned short s[8]; bf16x8 v; };

constexpr int D_ = 1024, L_ = 2048;
constexpr int CN = 384;   // Cbig row stride (floats)

// Wb2 blocked layout: W3[hh][vp][dt][quad][m][8]
__device__ inline size_t w3idx(int row, int col){
  const int hh = row >> 6, m = row & 15, dt = (row >> 4) & 3;
  const int vp = col >> 5, quad = (col >> 3) & 3, j = col & 7;
  return (size_t)hh*18432 + vp*2048 + dt*512 + quad*128 + m*8 + j;
}
// wo4 blocked layout for in-fused out-GEMM B-operand:
// wo4[e>>4][d>>5][(d>>3)&3][e&15][d&7]; per-(colgrp,c) wave load = base + lane*8 (1KB contiguous)
__device__ inline size_t wo4idx(int e, int d){
  return ((size_t)(e>>4)<<14) + ((size_t)(d>>5)<<9) + (((d>>3)&3)<<7) + ((e&15)<<3) + (d&7);
}

// ---------------------------------------------------------------------------
// merged prep v5: [0,4096) mcvt (wv->Ab, wo->wo4 BLOCKED, pe->pe_b);
// [4096,4352) tpB; [4352,4368) q+qwk READ-ONCE (1 block per hh)
__global__ __launch_bounds__(256) void k_prep2(const float* __restrict__ wv, const float* __restrict__ wo,
                                               const float* __restrict__ pe,
                                               const float* __restrict__ proj_w, const float* __restrict__ proj_b,
                                               const float* __restrict__ ce, const float* __restrict__ cq,
                                               const float* __restrict__ wq, const float* __restrict__ bq,
                                               const float* __restrict__ wk,
                                               unsigned short* __restrict__ Ab, unsigned short* __restrict__ wo4,
                                               unsigned short* __restrict__ pe_b,
                                               unsigned short* __restrict__ Btb){
  __shared__ float t[64][17];
  __shared__ float qL[64];
  const int blk = blockIdx.x;
  const int tid = threadIdx.x;
  if (blk < 4096){           // ---- mcvt
    int i = blk*256 + tid;   // float4-quad index
    if (i < 262144){
      float4 v = *(const float4*)(wv + (size_t)i*4);
      *(ushort4*)(Ab + (size_t)i*4) = make_ushort4(f2bu(v.x), f2bu(v.y), f2bu(v.z), f2bu(v.w));
    } else if (i < 524288){  // wo -> wo4 blocked (same values, permuted addresses)
      size_t off = i - 262144;
      int q = (int)(off*4); int e = q >> 10, d = q & 1023;  // 4 consecutive d, same 8-group half
      float4 v = *(const float4*)(wo + (size_t)off*4);
      *(ushort4*)(wo4 + wo4idx(e, d)) = make_ushort4(f2bu(v.x), f2bu(v.y), f2bu(v.z), f2bu(v.w));
    } else {
      size_t off = i - 524288;
      float4 v = *(const float4*)(pe + off*4);
      *(ushort4*)(pe_b + off*4) = make_ushort4(f2bu(v.x), f2bu(v.y), f2bu(v.z), f2bu(v.w));
    }
  } else if (blk < 4352){    // ---- tpB
    const int r_ = blk - 4096;
    const int v = r_ >> 4, dd0 = (r_ & 15)*64;
    { const int r = tid >> 2, kq = tid & 3;
      float4 a = *(const float4*)(proj_w + ((size_t)(v*D_ + dd0 + r))*16 + kq*4);
      t[r][kq*4+0]=a.x; t[r][kq*4+1]=a.y; t[r][kq*4+2]=a.z; t[r][kq*4+3]=a.w; }
    __syncthreads();
    { const int k = tid >> 4, c0 = (tid & 15)*4;
      ushort4 o = make_ushort4(f2bu(t[c0+0][k]), f2bu(t[c0+1][k]), f2bu(t[c0+2][k]), f2bu(t[c0+3][k]));
      *(ushort4*)(Btb + (size_t)(v*16+k)*D_ + dd0 + c0) = o; }
    if (tid < 16){
      const int c0 = tid*4;
      float4 pb = *(const float4*)(proj_b + v*D_ + dd0 + c0);
      float4 cc = *(const float4*)(ce     + v*D_ + dd0 + c0);
      ushort4 o = make_ushort4(f2bu(pb.x+cc.x), f2bu(pb.y+cc.y), f2bu(pb.z+cc.z), f2bu(pb.w+cc.w));
      *(ushort4*)(Btb + (size_t)(256+v)*D_ + dd0 + c0) = o;
    }
  } else {                   // ---- q + qwk, ONE block per hh (wq/wk read once)
    const int hh = blk - 4352;
    const int wave = tid >> 6, lane = tid & 63;
    {
      float cqv[16];
      #pragma unroll
      for (int k=0;k<16;++k) cqv[k] = cq[lane + 64*k];
      #pragma unroll
      for (int j=0;j<16;++j){
        const int e = hh*64 + wave*16 + j;
        const float* wr = wq + (size_t)e*D_;
        float p = 0.f;
        #pragma unroll
        for (int k=0;k<16;++k) p += cqv[k]*wr[lane + 64*k];
        #pragma unroll
        for (int m=32;m>=1;m>>=1) p += __shfl_xor(p, m, 64);
        if (lane==0) qL[wave*16+j] = p + bq[e];
      }
    }
    __syncthreads();
    #pragma unroll
    for (int dd=0; dd<4; ++dd){
      const int d = dd*256 + tid;          // coalesced across threads
      float s0=0.f, s1=0.f, s2=0.f, s3=0.f;
      #pragma unroll
      for (int j=0;j<16;++j) s0 += qL[j]    * wk[(size_t)(hh*64      + j)*D_ + d];
      #pragma unroll
      for (int j=0;j<16;++j) s1 += qL[16+j] * wk[(size_t)(hh*64 + 16 + j)*D_ + d];
      #pragma unroll
      for (int j=0;j<16;++j) s2 += qL[32+j] * wk[(size_t)(hh*64 + 32 + j)*D_ + d];
      #pragma unroll
      for (int j=0;j<16;++j) s3 += qL[48+j] * wk[(size_t)(hh*64 + 48 + j)*D_ + d];
      Ab[(size_t)(1024+hh)*D_ + d] = f2bu(((s0+s1)+(s2+s3))*0.125f);   // same tree order
    }
  }
}

// ---------------------------------------------------------------------------
// GEMM body v4 (R12-verified): BK=128 (8 k-steps for K=1024). BM = MFRAG*32, BN=128.
template<int MFRAG, bool BIAS, bool WB2>
__device__ inline void gemm_body(unsigned short* As, unsigned short* Bs,
                                 const unsigned short* __restrict__ Abf, const unsigned short* __restrict__ Bt,
                                 const float* __restrict__ bias, float* __restrict__ C,
                                 unsigned short* __restrict__ W, const float* __restrict__ bvp,
                                 int m0, int n0, int K, int ldc, int Mvalid){
  const int tid = threadIdx.x;
  const int wave = tid >> 6, lane = tid & 63;
  const int wm = wave & 1, wn = wave >> 1;
  const int lm = lane & 15, kg4 = lane >> 4;
  f32x4 acc[MFRAG][4];
  #pragma unroll
  for (int mf=0;mf<MFRAG;++mf)
    #pragma unroll
    for (int nf=0;nf<4;++nf) acc[mf][nf] = (f32x4){0.f,0.f,0.f,0.f};
  for (int k0=0; k0<K; k0+=128){
    #pragma unroll
    for (int i=0;i<2*MFRAG;++i){            // A: MFRAG*32 rows x 128 cols
      int idx = i*256 + tid;
      int row = idx >> 4, g = (idx & 15) ^ (row & 7);
      async_cp16(Abf + (size_t)(m0+row)*K + k0 + g*8, &As[idx*8]);
    }
    #pragma unroll
    for (int i=0;i<8;++i){                  // B: 128 rows x 128 cols
      int idx = i*256 + tid;
      int row = idx >> 4, g = (idx & 15) ^ (row & 7);
      async_cp16(Bt + (size_t)(n0+row)*K + k0 + g*8, &Bs[idx*8]);
    }
    __syncthreads();
    #pragma unroll
    for (int c=0;c<4;++c){
      bf16x8 af[MFRAG], bfr[4];
      #pragma unroll
      for (int f=0;f<MFRAG;++f){
        int row = wm*16*MFRAG + f*16 + lm;
        af[f] = *(const bf16x8*)(&As[row*128 + (((c*4+kg4) ^ (row&7)))*8]);
      }
      #pragma unroll
      for (int f=0;f<4;++f){
        int colr = wn*64 + f*16 + lm;
        bfr[f] = *(const bf16x8*)(&Bs[colr*128 + (((c*4+kg4) ^ (colr&7)))*8]);
      }
      #pragma unroll
      for (int mf=0;mf<MFRAG;++mf)
        #pragma unroll
        for (int nf=0;nf<4;++nf)
          acc[mf][nf] = __builtin_amdgcn_mfma_f32_16x16x32_bf16(af[mf], bfr[nf], acc[mf][nf], 0,0,0);
    }
    __syncthreads();
  }
  #pragma unroll
  for (int nf=0;nf<4;++nf){
    int col = n0 + wn*64 + nf*16 + lm;
    float bval = BIAS ? bias[col] : 0.f;
    #pragma unroll
    for (int mf=0;mf<MFRAG;++mf){
      #pragma unroll
      for (int r=0;r<4;++r){
        int row = m0 + wm*16*MFRAG + mf*16 + kg4*4 + r;
        if (row < Mvalid){
          float v = acc[mf][nf][r];
          C[(size_t)row*ldc + col] = v + bval;
          if (WB2 && row < 1024){
            if (col < 256)      W[w3idx(row,col)] = f2bu(v);
            else if (col < 272) W[w3idx(row,col)] = f2bu(v + bvp[row]);
            else if (col < 288) W[w3idx(row,col)] = 0;
          }
        }
      }
    }
  }
}

// merged: [0,51) Cbig GEMM BM=64 (+W3 blocked side-write); [51,563) P2 GEMM BM=32 (pe_b async)
__global__ __launch_bounds__(256) void k_gemmCP2(const unsigned short* __restrict__ Ab,
                                                 const unsigned short* __restrict__ Btb,
                                                 const unsigned short* __restrict__ pe_b,
                                                 const float* __restrict__ bv,
                                                 float* __restrict__ Cbig, unsigned short* __restrict__ Wb2,
                                                 float* __restrict__ P2){
  __shared__ unsigned short As[64*128];    // 16 KB
  __shared__ unsigned short Bs[128*128];   // 32 KB
  if (blockIdx.x < 51){
    int bx = blockIdx.x % 3, by = blockIdx.x / 3;
    gemm_body<2,false,true>(As, Bs, Ab, Btb, nullptr, Cbig, Wb2, bv, by*64, bx*128, 1024, CN, 1040);
  } else {
    int b = blockIdx.x - 51;          // bx = b>>6 (8 n-tiles), by = b&63 (64 m-tiles of 32)
    int bx = b >> 6, by = b & 63;
    gemm_body<1,false,false>(As, Bs, pe_b, Ab, nullptr, P2, nullptr, nullptr, by*32, bx*128, 1024, 1024, 2048);
  }
}

// ---------------------------------------------------------------------------
// fused v11: hqq-merged attention + IN-FUSED out-GEMM (4th kernel eliminated).
// grid 256 = bb(2) x sg(128); 1024 threads (16 waves).
// After S (16 ctx rows, bf16) is staged in LDS, each wave computes out cols
// [w*64, w*64+64) for the 16 rows: A from LDS S, B from blocked wo4 (1KB/wave L2 loads),
// NO barriers in the out section. k-order ascending 32-chunks == old BK=128 kernel
// -> bit-identical accumulation.
__global__ __launch_bounds__(1024) void k_fused11(const float* __restrict__ x,
                                                  const float* __restrict__ Cbig,
                                                  const unsigned short* __restrict__ W3,
                                                  const float* __restrict__ P2,
                                                  const unsigned short* __restrict__ wo4,
                                                  const float* __restrict__ bo,
                                                  float* __restrict__ out){
  __shared__ float patchP[16*260];   // [s][v*16+k]
  __shared__ float attnT[16*320];    // [h][s*20+v]
  __shared__ __align__(16) unsigned short S[16*1032];  // staged bf16 ctx tile [s][1024+pad]
  const int tid = threadIdx.x;
  const int bb  = blockIdx.x >> 7;
  const int sg  = blockIdx.x & 127;
  const int l0 = sg*16;
  { // phase A: thread (v, pi, u): one float4 each
    const int u = tid & 15, pi = (tid >> 4) & 3, v = tid >> 6;
    const int hi = l0 >> 6, wi0 = l0 & 63;
    const float* xp = x + ((size_t)((bb*16+v)*128 + hi*4 + pi)*256 + (wi0+u)*4);
    float4 r = *(const float4*)xp;
    float* dst = &patchP[u*260 + v*16 + pi*4];
    dst[0]=r.x; dst[1]=r.y; dst[2]=r.z; dst[3]=r.w;
  }
  __syncthreads();
  if (tid < 256){ // phase B: thread (s, h): scores + softmax -> attnT (float4 reads)
    const int s = tid >> 4, h = tid & 15;
    const float* qrow = Cbig + (size_t)(1024+h)*CN;
    const float* prow = &patchP[s*260];
    float4 qc0 = *(const float4*)(qrow+256);
    float4 qc1 = *(const float4*)(qrow+260);
    float4 qc2 = *(const float4*)(qrow+264);
    float4 qc3 = *(const float4*)(qrow+268);
    float qcv[16] = {qc0.x,qc0.y,qc0.z,qc0.w, qc1.x,qc1.y,qc1.z,qc1.w,
                     qc2.x,qc2.y,qc2.z,qc2.w, qc3.x,qc3.y,qc3.z,qc3.w};
    float sc[16];
    #pragma unroll
    for (int v=0; v<16; ++v){
      const float* qp = qrow + v*16;
      const float* pp = prow + v*16;
      float4 qa = *(const float4*)(qp+0),  qb = *(const float4*)(qp+4);
      float4 qc = *(const float4*)(qp+8),  qd = *(const float4*)(qp+12);
      float4 pa = *(const float4*)(pp+0),  pb2 = *(const float4*)(pp+4);
      float4 pc = *(const float4*)(pp+8),  pd = *(const float4*)(pp+12);
      float a = qcv[v];
      a += qa.x*pa.x + qa.y*pa.y + qa.z*pa.z + qa.w*pa.w;
      a += qb.x*pb2.x + qb.y*pb2.y + qb.z*pb2.z + qb.w*pb2.w;
      a += qc.x*pc.x + qc.y*pc.y + qc.z*pc.z + qc.w*pc.w;
      a += qd.x*pd.x + qd.y*pd.y + qd.z*pd.z + qd.w*pd.w;
      sc[v] = a;
    }
    float mx = sc[0];
    #pragma unroll
    for (int v=1;v<16;++v) mx = fmaxf(mx, sc[v]);
    float sum = 0.f;
    #pragma unroll
    for (int v=0;v<16;++v){ sc[v] = __expf(sc[v]-mx); sum += sc[v]; }
    float inv = 1.f/sum;
    float* arow = &attnT[h*320 + s*20];
    #pragma unroll
    for (int v=0;v<16;++v) arow[v] = sc[v]*inv;
  }
  __syncthreads();
  // phase C: wave = head hh (16 waves); 9 vp slices (8 patch + 1 attn-direct for c0+bv)
  const int wave = tid >> 6, lane = tid & 63;
  const int m = lane & 15, quad = lane >> 4;
  {
    const int hh = wave;
    const float* at = &attnT[hh*320];
    const unsigned short* wbase = W3 + (size_t)hh*18432 + lane*8;   // + vp*2048 + dt*512
    f32x4 acc[4];
    #pragma unroll
    for (int dt=0;dt<4;++dt) acc[dt] = (f32x4){0.f,0.f,0.f,0.f};
    #pragma unroll
    for (int vp=0; vp<9; ++vp){
      BF8 af;
      if (vp < 8){
        const int v = vp*2 + (quad>>1);
        const int k8 = (quad&1)*8;
        const float aw = at[m*20 + v];
        const float* pp = &patchP[m*260 + v*16 + k8];
        float4 p0 = *(const float4*)(pp+0);
        float4 p1 = *(const float4*)(pp+4);
        af.s[0]=f2bu(aw*p0.x); af.s[1]=f2bu(aw*p0.y); af.s[2]=f2bu(aw*p0.z); af.s[3]=f2bu(aw*p0.w);
        af.s[4]=f2bu(aw*p1.x); af.s[5]=f2bu(aw*p1.y); af.s[6]=f2bu(aw*p1.z); af.s[7]=f2bu(aw*p1.w);
      } else {
        #pragma unroll
        for (int j=0;j<8;++j)
          af.s[j] = (quad < 2) ? f2bu(at[m*20 + quad*8 + j]) : (unsigned short)0;
      }
      #pragma unroll
      for (int dt=0; dt<4; ++dt){
        const bf16x8 bf = *(const bf16x8*)(wbase + vp*2048 + dt*512);
        acc[dt] = __builtin_amdgcn_mfma_f32_16x16x32_bf16(af.v, bf, acc[dt], 0,0,0);
      }
    }
    // stage ctx tile to LDS (P2-add + bf16 round, same math/order as before)
    #pragma unroll
    for (int dt=0; dt<4; ++dt){
      const int d = hh*64 + dt*16 + m;
      #pragma unroll
      for (int r=0;r<4;++r){
        const int s = quad*4 + r;
        S[s*1032 + d] = f2bu(acc[dt][r] + P2[(size_t)(l0+s)*D_ + d]);
      }
    }
  }
  __syncthreads();
  // out section (barrier-free): wave w computes out[l0..l0+15][w*64 .. w*64+63]
  {
    const int w = wave;
    const int lm = m, kg4 = quad;
    #pragma unroll
    for (int pass=0; pass<2; ++pass){
      f32x4 oacc[2];
      oacc[0] = (f32x4){0.f,0.f,0.f,0.f};
      oacc[1] = (f32x4){0.f,0.f,0.f,0.f};
      for (int c=0; c<32; ++c){
        const bf16x8 a8 = *(const bf16x8*)(&S[lm*1032 + (c*4+kg4)*8]);
        #pragma unroll
        for (int nf=0; nf<2; ++nf){
          const int colgrp = (w<<2) + pass*2 + nf;
          const bf16x8 b8 = *(const bf16x8*)(wo4 + ((size_t)colgrp<<14) + (c<<9) + lane*8);
          oacc[nf] = __builtin_amdgcn_mfma_f32_16x16x32_bf16(a8, b8, oacc[nf], 0,0,0);
        }
      }
      #pragma unroll
      for (int nf=0; nf<2; ++nf){
        const int col = w*64 + (pass*2+nf)*16 + lm;
        const float bval = bo[col];
        #pragma unroll
        for (int r=0;r<4;++r){
          const int row = l0 + kg4*4 + r;
          out[(size_t)(bb*L_ + row)*D_ + col] = oacc[nf][r] + bval;
        }
      }
    }
  }
}

// ---------------------------------------------------------------------------
extern "C" void kernel_launch(void* const* d_in, const int* in_sizes, int n_in,
                              void* d_out, int out_size, void* d_ws, size_t ws_size,
                              hipStream_t stream){
  const float* x      = (const float*)d_in[0];
  const float* proj_w = (const float*)d_in[1];
  const float* proj_b = (const float*)d_in[2];
  const float* ce     = (const float*)d_in[3];
  const float* pe     = (const float*)d_in[4];
  const float* cq     = (const float*)d_in[5];
  const float* wq     = (const float*)d_in[6];
  const float* wk     = (const float*)d_in[7];
  const float* wv     = (const float*)d_in[8];
  const float* bq     = (const float*)d_in[9];
  // bk (d_in[10]) cancels in softmax
  const float* bv     = (const float*)d_in[11];
  const float* wo     = (const float*)d_in[12];
  const float* bo     = (const float*)d_in[13];
  float* out = (float*)d_out;

  // workspace — flat, ~28.4 MB used (ctxF now dead; layout kept)
  char* base = (char*)d_ws;
  unsigned short* Ab   = (unsigned short*)(base);              // [1152][1024] bf16 -> 2,359,296
  unsigned short* Btb  = (unsigned short*)(base + 2359296);    // [384][1024] bf16 -> 3,145,728
  float*          Cbig = (float*)(base + 3145728);             // [1040][384] f32 -> 4,743,168
  unsigned short* wo4  = (unsigned short*)(base + 4743168);    // wo blocked [1024x1024] bf16 -> 6,840,320
  unsigned short* Wb2  = (unsigned short*)(base + 6840320);    // W3 blocked [1024x288] bf16 -> 7,430,144
  float*          P2   = (float*)(base + 7430144);             // [2048][1024] f32 -> 15,818,752
  unsigned short* pe_b = (unsigned short*)(base + 15818752);   // [2048][1024] bf16 -> 20,013,056

  // 1) prep v5: mcvt (wv, wo->wo4 blocked, pe) | tpB | q+qwk read-once (16 blocks)
  k_prep2<<<4368, 256, 0, stream>>>(wv, wo, pe, proj_w, proj_b, ce, cq, wq, bq, wk, Ab, wo4, pe_b, Btb);
  // 2) Cbig (+W3 blocked side-write)  ||  P2 = pe_b·wv^T   (BK=128: 8 k-steps)
  k_gemmCP2<<<563, 256, 0, stream>>>(Ab, Btb, pe_b, bv, Cbig, Wb2, P2);
  // 3) fused attention + out-GEMM -> out directly (3 kernels total)
  k_fused11<<<256, 1024, 0, stream>>>(x, Cbig, Wb2, P2, wo4, bo, out);
}

// Round 14
// 168.672 us; speedup vs baseline: 1.0190x; 1.0190x over previous
//
#include <hip/hip_runtime.h>
#include <hip/hip_bf16.h>

using bf16 = __hip_bfloat16;
using bf16x8 = __attribute__((ext_vector_type(8))) short;
using f32x4  = __attribute__((ext_vector_type(4))) float;

__device__ inline unsigned short f2bu(float f){ bf16 h = __float2bfloat16(f); return *(unsigned short*)&h; }
__device__ inline void async_cp16(const void* g, void* l){
  __builtin_amdgcn_global_load_lds((const __attribute__((address_space(1))) void*)g,
                                   (__attribute__((address_space(3))) void*)l, 16, 0, 0);
}
union BF8 { unsigned short s[8]; bf16x8 v; };

constexpr int D_ = 1024, L_ = 2048;
constexpr int CN = 384;   // Cbig row stride (floats)

// Wb2 blocked layout: W3[hh][vp][dt][quad][m][8]
__device__ inline size_t w3idx(int row, int col){
  const int hh = row >> 6, m = row & 15, dt = (row >> 4) & 3;
  const int vp = col >> 5, quad = (col >> 3) & 3, j = col & 7;
  return (size_t)hh*18432 + vp*2048 + dt*512 + quad*128 + m*8 + j;
}

// ---------------------------------------------------------------------------
// merged prep v4 (R12-verified): [0,4096) mcvt (wv->Ab, wo->wo_b, pe->pe_b);
// [4096,4352) tpB; [4352,4368) q+qwk READ-ONCE (1 block per hh)
__global__ __launch_bounds__(256) void k_prep2(const float* __restrict__ wv, const float* __restrict__ wo,
                                               const float* __restrict__ pe,
                                               const float* __restrict__ proj_w, const float* __restrict__ proj_b,
                                               const float* __restrict__ ce, const float* __restrict__ cq,
                                               const float* __restrict__ wq, const float* __restrict__ bq,
                                               const float* __restrict__ wk,
                                               unsigned short* __restrict__ Ab, unsigned short* __restrict__ wo_b,
                                               unsigned short* __restrict__ pe_b,
                                               unsigned short* __restrict__ Btb){
  __shared__ float t[64][17];
  __shared__ float qL[64];
  const int blk = blockIdx.x;
  const int tid = threadIdx.x;
  if (blk < 4096){           // ---- mcvt
    int i = blk*256 + tid;   // float4-quad index
    const float* src; unsigned short* dst; size_t off;
    if (i < 262144){ src = wv; dst = Ab;   off = i; }
    else if (i < 524288){ src = wo; dst = wo_b; off = i - 262144; }
    else           { src = pe; dst = pe_b; off = i - 524288; }
    float4 v = *(const float4*)(src + off*4);
    *(ushort4*)(dst + off*4) = make_ushort4(f2bu(v.x), f2bu(v.y), f2bu(v.z), f2bu(v.w));
  } else if (blk < 4352){    // ---- tpB
    const int r_ = blk - 4096;
    const int v = r_ >> 4, dd0 = (r_ & 15)*64;
    { const int r = tid >> 2, kq = tid & 3;
      float4 a = *(const float4*)(proj_w + ((size_t)(v*D_ + dd0 + r))*16 + kq*4);
      t[r][kq*4+0]=a.x; t[r][kq*4+1]=a.y; t[r][kq*4+2]=a.z; t[r][kq*4+3]=a.w; }
    __syncthreads();
    { const int k = tid >> 4, c0 = (tid & 15)*4;
      ushort4 o = make_ushort4(f2bu(t[c0+0][k]), f2bu(t[c0+1][k]), f2bu(t[c0+2][k]), f2bu(t[c0+3][k]));
      *(ushort4*)(Btb + (size_t)(v*16+k)*D_ + dd0 + c0) = o; }
    if (tid < 16){
      const int c0 = tid*4;
      float4 pb = *(const float4*)(proj_b + v*D_ + dd0 + c0);
      float4 cc = *(const float4*)(ce     + v*D_ + dd0 + c0);
      ushort4 o = make_ushort4(f2bu(pb.x+cc.x), f2bu(pb.y+cc.y), f2bu(pb.z+cc.z), f2bu(pb.w+cc.w));
      *(ushort4*)(Btb + (size_t)(256+v)*D_ + dd0 + c0) = o;
    }
  } else {                   // ---- q + qwk, ONE block per hh (wq/wk read once)
    const int hh = blk - 4352;
    const int wave = tid >> 6, lane = tid & 63;
    {
      float cqv[16];
      #pragma unroll
      for (int k=0;k<16;++k) cqv[k] = cq[lane + 64*k];
      #pragma unroll
      for (int j=0;j<16;++j){
        const int e = hh*64 + wave*16 + j;
        const float* wr = wq + (size_t)e*D_;
        float p = 0.f;
        #pragma unroll
        for (int k=0;k<16;++k) p += cqv[k]*wr[lane + 64*k];
        #pragma unroll
        for (int m=32;m>=1;m>>=1) p += __shfl_xor(p, m, 64);
        if (lane==0) qL[wave*16+j] = p + bq[e];
      }
    }
    __syncthreads();
    #pragma unroll
    for (int dd=0; dd<4; ++dd){
      const int d = dd*256 + tid;          // coalesced across threads
      float s0=0.f, s1=0.f, s2=0.f, s3=0.f;
      #pragma unroll
      for (int j=0;j<16;++j) s0 += qL[j]    * wk[(size_t)(hh*64      + j)*D_ + d];
      #pragma unroll
      for (int j=0;j<16;++j) s1 += qL[16+j] * wk[(size_t)(hh*64 + 16 + j)*D_ + d];
      #pragma unroll
      for (int j=0;j<16;++j) s2 += qL[32+j] * wk[(size_t)(hh*64 + 32 + j)*D_ + d];
      #pragma unroll
      for (int j=0;j<16;++j) s3 += qL[48+j] * wk[(size_t)(hh*64 + 48 + j)*D_ + d];
      Ab[(size_t)(1024+hh)*D_ + d] = f2bu(((s0+s1)+(s2+s3))*0.125f);   // same tree order
    }
  }
}

// ---------------------------------------------------------------------------
// GEMM body v4 (R12-verified): BK=128 (8 k-steps for K=1024). BM = MFRAG*32, BN=128.
template<int MFRAG, bool BIAS, bool WB2>
__device__ inline void gemm_body(unsigned short* As, unsigned short* Bs,
                                 const unsigned short* __restrict__ Abf, const unsigned short* __restrict__ Bt,
                                 const float* __restrict__ bias, float* __restrict__ C,
                                 unsigned short* __restrict__ W, const float* __restrict__ bvp,
                                 int m0, int n0, int K, int ldc, int Mvalid){
  const int tid = threadIdx.x;
  const int wave = tid >> 6, lane = tid & 63;
  const int wm = wave & 1, wn = wave >> 1;
  const int lm = lane & 15, kg4 = lane >> 4;
  f32x4 acc[MFRAG][4];
  #pragma unroll
  for (int mf=0;mf<MFRAG;++mf)
    #pragma unroll
    for (int nf=0;nf<4;++nf) acc[mf][nf] = (f32x4){0.f,0.f,0.f,0.f};
  for (int k0=0; k0<K; k0+=128){
    #pragma unroll
    for (int i=0;i<2*MFRAG;++i){            // A: MFRAG*32 rows x 128 cols
      int idx = i*256 + tid;
      int row = idx >> 4, g = (idx & 15) ^ (row & 7);
      async_cp16(Abf + (size_t)(m0+row)*K + k0 + g*8, &As[idx*8]);
    }
    #pragma unroll
    for (int i=0;i<8;++i){                  // B: 128 rows x 128 cols
      int idx = i*256 + tid;
      int row = idx >> 4, g = (idx & 15) ^ (row & 7);
      async_cp16(Bt + (size_t)(n0+row)*K + k0 + g*8, &Bs[idx*8]);
    }
    __syncthreads();
    #pragma unroll
    for (int c=0;c<4;++c){
      bf16x8 af[MFRAG], bfr[4];
      #pragma unroll
      for (int f=0;f<MFRAG;++f){
        int row = wm*16*MFRAG + f*16 + lm;
        af[f] = *(const bf16x8*)(&As[row*128 + (((c*4+kg4) ^ (row&7)))*8]);
      }
      #pragma unroll
      for (int f=0;f<4;++f){
        int colr = wn*64 + f*16 + lm;
        bfr[f] = *(const bf16x8*)(&Bs[colr*128 + (((c*4+kg4) ^ (colr&7)))*8]);
      }
      #pragma unroll
      for (int mf=0;mf<MFRAG;++mf)
        #pragma unroll
        for (int nf=0;nf<4;++nf)
          acc[mf][nf] = __builtin_amdgcn_mfma_f32_16x16x32_bf16(af[mf], bfr[nf], acc[mf][nf], 0,0,0);
    }
    __syncthreads();
  }
  #pragma unroll
  for (int nf=0;nf<4;++nf){
    int col = n0 + wn*64 + nf*16 + lm;
    float bval = BIAS ? bias[col] : 0.f;
    #pragma unroll
    for (int mf=0;mf<MFRAG;++mf){
      #pragma unroll
      for (int r=0;r<4;++r){
        int row = m0 + wm*16*MFRAG + mf*16 + kg4*4 + r;
        if (row < Mvalid){
          float v = acc[mf][nf][r];
          C[(size_t)row*ldc + col] = v + bval;
          if (WB2 && row < 1024){
            if (col < 256)      W[w3idx(row,col)] = f2bu(v);
            else if (col < 272) W[w3idx(row,col)] = f2bu(v + bvp[row]);
            else if (col < 288) W[w3idx(row,col)] = 0;
          }
        }
      }
    }
  }
}

// merged: [0,51) Cbig GEMM BM=64 (+W3 blocked side-write); [51,563) P2 GEMM BM=32 (pe_b async)
__global__ __launch_bounds__(256) void k_gemmCP2(const unsigned short* __restrict__ Ab,
                                                 const unsigned short* __restrict__ Btb,
                                                 const unsigned short* __restrict__ pe_b,
                                                 const float* __restrict__ bv,
                                                 float* __restrict__ Cbig, unsigned short* __restrict__ Wb2,
                                                 float* __restrict__ P2){
  __shared__ unsigned short As[64*128];    // 16 KB
  __shared__ unsigned short Bs[128*128];   // 32 KB
  if (blockIdx.x < 51){
    int bx = blockIdx.x % 3, by = blockIdx.x / 3;
    gemm_body<2,false,true>(As, Bs, Ab, Btb, nullptr, Cbig, Wb2, bv, by*64, bx*128, 1024, CN, 1040);
  } else {
    int b = blockIdx.x - 51;          // bx = b>>6 (8 n-tiles), by = b&63 (64 m-tiles of 32)
    int bx = b >> 6, by = b & 63;
    gemm_body<1,false,false>(As, Bs, pe_b, Ab, nullptr, P2, nullptr, nullptr, by*32, bx*128, 1024, 1024, 2048);
  }
}

// out GEMM: out[4096][1024] = ctxF·wo_b^T + bo ; BM=64 (MFRAG=2), BK=128, grid dim3(64,8)
__global__ __launch_bounds__(256) void k_gemmOut(const unsigned short* __restrict__ ctxF,
                                                 const unsigned short* __restrict__ wo_b,
                                                 const float* __restrict__ bo, float* __restrict__ C){
  __shared__ unsigned short As[64*128];
  __shared__ unsigned short Bs[128*128];
  gemm_body<2,true,false>(As, Bs, ctxF, wo_b, bo, C, nullptr, nullptr,
                          blockIdx.x*64, blockIdx.y*128, 1024, 1024, 4096);
}

// ---------------------------------------------------------------------------
// fused v12: HEAD-SPLIT for 2 blocks/CU. grid 512 = bb(2) x sg(128) x hp(2);
// 512 threads (8 waves). Each block: 16-token tile, 8 heads (d-columns hp*512..+512).
// Tokens stay 16 -> full MFMA tiles. LDS 43.5 KB -> 3 blocks/CU by LDS, 2 co-resident
// from grid -> barriers/partial-wave phases overlap across blocks (R13's 1-block/CU
// starvation fixed). Per-element math identical to fused10 -> bit-identical output.
__global__ __launch_bounds__(512) void k_fused12(const float* __restrict__ x,
                                                 const float* __restrict__ Cbig,
                                                 const unsigned short* __restrict__ W3,
                                                 const float* __restrict__ P2,
                                                 unsigned short* __restrict__ ctxF){
  __shared__ float patchP[16*260];   // [s][v*16+k]
  __shared__ float attnT[8*320];     // [hl][s*20+v]
  __shared__ __align__(16) unsigned short S[16*520];  // staged bf16 ctx half-tile [s][512+pad]
  const int tid = threadIdx.x;
  const int bb  = blockIdx.x >> 8;
  const int sg  = (blockIdx.x >> 1) & 127;
  const int hp  = blockIdx.x & 1;
  unsigned short* ctx = ctxF + (size_t)bb*L_*D_;
  const int l0 = sg*16;
  { // phase A: 512 threads, 2 float4 loads each (v8 and v8+8)
    const int u = tid & 15, pi = (tid >> 4) & 3, v8 = tid >> 6;   // v8 in 0..7
    const int hi = l0 >> 6, wi0 = l0 & 63;
    #pragma unroll
    for (int vv = v8; vv < 16; vv += 8){
      const float* xp = x + ((size_t)((bb*16+vv)*128 + hi*4 + pi)*256 + (wi0+u)*4);
      float4 r = *(const float4*)xp;
      float* dst = &patchP[u*260 + vv*16 + pi*4];
      dst[0]=r.x; dst[1]=r.y; dst[2]=r.z; dst[3]=r.w;
    }
  }
  __syncthreads();
  if (tid < 128){ // phase B: thread (s, hl): h = hp*8+hl; scores + softmax -> attnT
    const int s = tid >> 3, hl = tid & 7;
    const int h = hp*8 + hl;
    const float* qrow = Cbig + (size_t)(1024+h)*CN;
    const float* prow = &patchP[s*260];
    float4 qc0 = *(const float4*)(qrow+256);
    float4 qc1 = *(const float4*)(qrow+260);
    float4 qc2 = *(const float4*)(qrow+264);
    float4 qc3 = *(const float4*)(qrow+268);
    float qcv[16] = {qc0.x,qc0.y,qc0.z,qc0.w, qc1.x,qc1.y,qc1.z,qc1.w,
                     qc2.x,qc2.y,qc2.z,qc2.w, qc3.x,qc3.y,qc3.z,qc3.w};
    float sc[16];
    #pragma unroll
    for (int v=0; v<16; ++v){
      const float* qp = qrow + v*16;
      const float* pp = prow + v*16;
      float4 qa = *(const float4*)(qp+0),  qb = *(const float4*)(qp+4);
      float4 qc = *(const float4*)(qp+8),  qd = *(const float4*)(qp+12);
      float4 pa = *(const float4*)(pp+0),  pb2 = *(const float4*)(pp+4);
      float4 pc = *(const float4*)(pp+8),  pd = *(const float4*)(pp+12);
      float a = qcv[v];
      a += qa.x*pa.x + qa.y*pa.y + qa.z*pa.z + qa.w*pa.w;
      a += qb.x*pb2.x + qb.y*pb2.y + qb.z*pb2.z + qb.w*pb2.w;
      a += qc.x*pc.x + qc.y*pc.y + qc.z*pc.z + qc.w*pc.w;
      a += qd.x*pd.x + qd.y*pd.y + qd.z*pd.z + qd.w*pd.w;
      sc[v] = a;
    }
    float mx = sc[0];
    #pragma unroll
    for (int v=1;v<16;++v) mx = fmaxf(mx, sc[v]);
    float sum = 0.f;
    #pragma unroll
    for (int v=0;v<16;++v){ sc[v] = __expf(sc[v]-mx); sum += sc[v]; }
    float inv = 1.f/sum;
    float* arow = &attnT[hl*320 + s*20];
    #pragma unroll
    for (int v=0;v<16;++v) arow[v] = sc[v]*inv;
  }
  __syncthreads();
  // phase C: wave = local head (8 waves); global hh = hp*8 + wave
  const int wave = tid >> 6, lane = tid & 63;
  const int m = lane & 15, quad = lane >> 4;
  const int hh = hp*8 + wave;
  const float* at = &attnT[wave*320];
  const unsigned short* wbase = W3 + (size_t)hh*18432 + lane*8;   // + vp*2048 + dt*512
  f32x4 acc[4];
  #pragma unroll
  for (int dt=0;dt<4;++dt) acc[dt] = (f32x4){0.f,0.f,0.f,0.f};
  #pragma unroll
  for (int vp=0; vp<9; ++vp){
    BF8 af;
    if (vp < 8){
      const int v = vp*2 + (quad>>1);
      const int k8 = (quad&1)*8;
      const float aw = at[m*20 + v];
      const float* pp = &patchP[m*260 + v*16 + k8];
      float4 p0 = *(const float4*)(pp+0);
      float4 p1 = *(const float4*)(pp+4);
      af.s[0]=f2bu(aw*p0.x); af.s[1]=f2bu(aw*p0.y); af.s[2]=f2bu(aw*p0.z); af.s[3]=f2bu(aw*p0.w);
      af.s[4]=f2bu(aw*p1.x); af.s[5]=f2bu(aw*p1.y); af.s[6]=f2bu(aw*p1.z); af.s[7]=f2bu(aw*p1.w);
    } else {
      #pragma unroll
      for (int j=0;j<8;++j)
        af.s[j] = (quad < 2) ? f2bu(at[m*20 + quad*8 + j]) : (unsigned short)0;
    }
    #pragma unroll
    for (int dt=0; dt<4; ++dt){
      const bf16x8 bf = *(const bf16x8*)(wbase + vp*2048 + dt*512);
      acc[dt] = __builtin_amdgcn_mfma_f32_16x16x32_bf16(af.v, bf, acc[dt], 0,0,0);
    }
  }
  // epilogue: stage half-tile to LDS (P2-add + bf16 round, same math/order), coalesced write
  #pragma unroll
  for (int dt=0; dt<4; ++dt){
    const int dl = wave*64 + dt*16 + m;          // local d in [0,512)
    const int d  = hp*512 + dl;                  // global d
    #pragma unroll
    for (int r=0;r<4;++r){
      const int s = quad*4 + r;
      S[s*520 + dl] = f2bu(acc[dt][r] + P2[(size_t)(l0+s)*D_ + d]);
    }
  }
  __syncthreads();
  {
    const int row = tid >> 5, ch = tid & 31;     // 16 rows x 32 chunks of 32 B
    const unsigned short* srcp = &S[row*520 + ch*16];
    unsigned short* dstp = ctx + (size_t)(l0+row)*D_ + hp*512 + ch*16;
    *(uint4*)(dstp)   = *(const uint4*)(srcp);
    *(uint4*)(dstp+8) = *(const uint4*)(srcp+8);
  }
}

// ---------------------------------------------------------------------------
extern "C" void kernel_launch(void* const* d_in, const int* in_sizes, int n_in,
                              void* d_out, int out_size, void* d_ws, size_t ws_size,
                              hipStream_t stream){
  const float* x      = (const float*)d_in[0];
  const float* proj_w = (const float*)d_in[1];
  const float* proj_b = (const float*)d_in[2];
  const float* ce     = (const float*)d_in[3];
  const float* pe     = (const float*)d_in[4];
  const float* cq     = (const float*)d_in[5];
  const float* wq     = (const float*)d_in[6];
  const float* wk     = (const float*)d_in[7];
  const float* wv     = (const float*)d_in[8];
  const float* bq     = (const float*)d_in[9];
  // bk (d_in[10]) cancels in softmax
  const float* bv     = (const float*)d_in[11];
  const float* wo     = (const float*)d_in[12];
  const float* bo     = (const float*)d_in[13];
  float* out = (float*)d_out;

  // workspace — flat, ~28.4 MB used
  char* base = (char*)d_ws;
  unsigned short* Ab   = (unsigned short*)(base);              // [1152][1024] bf16 -> 2,359,296
  unsigned short* Btb  = (unsigned short*)(base + 2359296);    // [384][1024] bf16 -> 3,145,728
  float*          Cbig = (float*)(base + 3145728);             // [1040][384] f32 -> 4,743,168
  unsigned short* wo_b = (unsigned short*)(base + 4743168);    // [1024][1024] bf16 -> 6,840,320
  unsigned short* Wb2  = (unsigned short*)(base + 6840320);    // W3 blocked [1024x288] bf16 -> 7,430,144
  float*          P2   = (float*)(base + 7430144);             // [2048][1024] f32 -> 15,818,752
  unsigned short* ctxF = (unsigned short*)(base + 15818752);   // [4096][1024] bf16 -> 24,207,360
  unsigned short* pe_b = (unsigned short*)(base + 24207360);   // [2048][1024] bf16 -> 28,401,664

  // 1) prep v4: mcvt (wv,wo,pe) | tpB | q+qwk read-once (16 blocks)
  k_prep2<<<4368, 256, 0, stream>>>(wv, wo, pe, proj_w, proj_b, ce, cq, wq, bq, wk, Ab, wo_b, pe_b, Btb);
  // 2) Cbig (+W3 blocked side-write)  ||  P2 = pe_b·wv^T   (BK=128: 8 k-steps)
  k_gemmCP2<<<563, 256, 0, stream>>>(Ab, Btb, pe_b, bv, Cbig, Wb2, P2);
  // 3) fused attention -> ctxF (head-split: grid 512, 2 blocks/CU)
  k_fused12<<<512, 512, 0, stream>>>(x, Cbig, Wb2, P2, ctxF);
  // 4) out = ctxF·wo^T + bo   (BM=64, BK=128; grid (64,8))
  k_gemmOut<<<dim3(64,8), 256, 0, stream>>>(ctxF, wo_b, bo, out);
}